// Round 7
// baseline (1340.613 us; speedup 1.0000x reference)
//
#include <hip/hip_runtime.h>
#include <math.h>

// EncoderLayer (ABI two-stream transformer), bf16-MFMA implementation.
// B=8 S=1024 D=512 H=8 DK=DV=64 DFF=2048.
// d_out = [out_a | out_b | attn(8,8,1024,1024)] fp32.
// All GEMMs: NT-form MFMA 16x16x32 bf16, fp32 accum. LN/softmax fp32.

namespace {
constexpr int S_ = 1024, D_ = 512, H_ = 8;
constexpr int NROW_ = 8192;
constexpr float SCALE_ = 0.125f;
constexpr float EPS_ = 1e-5f;
constexpr size_t SLOT_ = (size_t)NROW_ * D_;  // 4,194,304 elements

typedef __attribute__((ext_vector_type(8))) short s16x8;   // MFMA bf16 operand
typedef __attribute__((ext_vector_type(4))) float f32x4;
typedef unsigned short u16;
typedef __attribute__((ext_vector_type(4))) u16 u16x4;
typedef __attribute__((ext_vector_type(8))) u16 u16x8;

__device__ __forceinline__ u16 f2bf(float f) {
  union { float f; unsigned int u; } v{f};
  unsigned int r = v.u + 0x7FFFu + ((v.u >> 16) & 1u);
  return (u16)(r >> 16);
}
__device__ __forceinline__ float bf2f(u16 u) {
  union { unsigned int u; float f; } v; v.u = ((unsigned int)u) << 16; return v.f;
}
__device__ __forceinline__ f32x4 mm(s16x8 a, s16x8 b, f32x4 c) {
  return __builtin_amdgcn_mfma_f32_16x16x32_bf16(a, b, c, 0, 0, 0);
}
}  // namespace

// ---------- fp32 -> bf16 cast (vectorized) ----------------------------------
__global__ __launch_bounds__(256) void cast_bf(const float* __restrict__ x,
                                               u16* __restrict__ y) {
  const int i = (blockIdx.x * 256 + threadIdx.x) * 4;
  const float4 v = *(const float4*)(x + i);
  u16x4 o = {f2bf(v.x), f2bf(v.y), f2bf(v.z), f2bf(v.w)};
  *(u16x4*)(y + i) = o;
}

// ---------- W[K,N] fp32 -> Wt[N,K] bf16 (tiled transpose) -------------------
__global__ __launch_bounds__(256) void wtrans(const float* __restrict__ W,
                                              u16* __restrict__ Wt, int K, int N) {
  __shared__ float T[64][65];
  const int t = threadIdx.x;
  const int n0 = blockIdx.x << 6, k0 = blockIdx.y << 6;
#pragma unroll
  for (int it = 0; it < 4; ++it) {
    const int kr = (t >> 4) + (it << 4);
    const float4 v = *(const float4*)(W + (size_t)(k0 + kr) * N + n0 + ((t & 15) << 2));
    T[kr][((t & 15) << 2) + 0] = v.x;
    T[kr][((t & 15) << 2) + 1] = v.y;
    T[kr][((t & 15) << 2) + 2] = v.z;
    T[kr][((t & 15) << 2) + 3] = v.w;
  }
  __syncthreads();
#pragma unroll
  for (int it = 0; it < 4; ++it) {
    const int nr = (t >> 4) + (it << 4);
    u16x4 o;
#pragma unroll
    for (int i = 0; i < 4; ++i) o[i] = f2bf(T[((t & 15) << 2) + i][nr]);
    *(u16x4*)(Wt + (size_t)(n0 + nr) * K + k0 + ((t & 15) << 2)) = o;
  }
}

// ---------- NT GEMM: C[M,N] = A[M,K] . Bt[N,K], bf16 in, bf16 out -----------
// 128x128 tile, BK=64, 256 thr = 4 waves (2x2), wave = 4x4 frags of 16x16.
// LDS XOR-swizzled (chunk ^ (row&7)) via pre-swizzled global source, linear write.
// VOUT=1: store C[m][n] to Vt layout [b,h,d,s] (m=b*1024+s, n=h*64+d).
template <int RELU, int VOUT>
__global__ __launch_bounds__(256) void gemm_nt(const u16* __restrict__ A,
                                               const u16* __restrict__ Bt,
                                               u16* __restrict__ C, int N, int K) {
  __shared__ __align__(16) u16 As[128 * 64];
  __shared__ __align__(16) u16 Bs[128 * 64];
  const int t = threadIdx.x, l = t & 63, w = t >> 6;
  const int row0 = blockIdx.y << 7, col0 = blockIdx.x << 7;
  const int wm = w >> 1, wn = w & 1;
  const int lr = l & 15, lg = l >> 4;
  const int xorv = (l & 7) << 4;  // byte-XOR for frag reads (row&7 == l&7)

  const u16* srcA[4]; const u16* srcB[4];
  u16* dstA[4]; u16* dstB[4];
#pragma unroll
  for (int i = 0; i < 4; ++i) {
    const int s = i * 256 + t;
    const int m = s >> 3;                       // tile row 0..127
    const int cg = (t & 7) ^ (m & 7);           // global chunk (pre-swizzle)
    srcA[i] = A + (size_t)(row0 + m) * K + cg * 8;
    srcB[i] = Bt + (size_t)(col0 + m) * K + cg * 8;
    dstA[i] = As + s * 8;                       // linear LDS write
    dstB[i] = Bs + s * 8;
  }
  f32x4 acc[4][4];
#pragma unroll
  for (int i = 0; i < 4; ++i)
#pragma unroll
    for (int j = 0; j < 4; ++j) acc[i][j] = (f32x4)0.f;

  const int nk = K >> 6;
  u16x8 ra[4], rb[4];
#pragma unroll
  for (int i = 0; i < 4; ++i) { ra[i] = *(const u16x8*)srcA[i]; rb[i] = *(const u16x8*)srcB[i]; }
  for (int ks = 0; ks < nk; ++ks) {
    __syncthreads();
#pragma unroll
    for (int i = 0; i < 4; ++i) { *(u16x8*)dstA[i] = ra[i]; *(u16x8*)dstB[i] = rb[i]; }
    __syncthreads();
    if (ks + 1 < nk) {
      const int k0 = (ks + 1) << 6;
#pragma unroll
      for (int i = 0; i < 4; ++i) {
        ra[i] = *(const u16x8*)(srcA[i] + k0);
        rb[i] = *(const u16x8*)(srcB[i] + k0);
      }
    }
#pragma unroll
    for (int kk = 0; kk < 2; ++kk) {
      s16x8 fa[4], fb[4];
      const int cb = (kk * 64 + lg * 16) ^ xorv;
#pragma unroll
      for (int f = 0; f < 4; ++f) {
        const int m = wm * 64 + f * 16 + lr;
        fa[f] = *(const s16x8*)((const char*)As + m * 128 + cb);
        const int n = wn * 64 + f * 16 + lr;
        fb[f] = *(const s16x8*)((const char*)Bs + n * 128 + cb);
      }
#pragma unroll
      for (int i = 0; i < 4; ++i)
#pragma unroll
        for (int j = 0; j < 4; ++j) acc[i][j] = mm(fa[i], fb[j], acc[i][j]);
    }
  }
#pragma unroll
  for (int i = 0; i < 4; ++i)
#pragma unroll
    for (int j = 0; j < 4; ++j)
#pragma unroll
      for (int r = 0; r < 4; ++r) {
        float v = acc[i][j][r];
        if (RELU) v = fmaxf(v, 0.f);
        const int m = row0 + wm * 64 + i * 16 + lg * 4 + r;
        const int n = col0 + wn * 64 + j * 16 + lr;
        size_t off;
        if (VOUT) {
          const int b = m >> 10, sq = m & 1023, h = n >> 6, d = n & 63;
          off = (((size_t)(b * H_ + h) * 64 + d) << 10) + sq;
        } else {
          off = (size_t)m * N + n;
        }
        C[off] = f2bf(v);
      }
}

// ---------- self-attention, flash MFMA --------------------------------------
// Q,K: [b,s,h,d] bf16; Vt: [b,h,d,s] bf16; O: [b,s,h,d] bf16.
// grid (S/64, H, B), 4 waves x 16 q-rows. Per 32-key tile: QK (4 MFMA) ->
// online softmax on C layout -> P via per-wave LDS -> PV (4 MFMA).
__global__ __launch_bounds__(256) void attn_flash(const u16* __restrict__ Q,
                                                  const u16* __restrict__ K,
                                                  const u16* __restrict__ Vt,
                                                  u16* __restrict__ O) {
  __shared__ __align__(16) u16 P_lds[4][16][40];  // 80B rows, 16B-aligned frag reads
  const int t = threadIdx.x, l = t & 63, w = t >> 6;
  const int lr = l & 15, lg = l >> 4;
  const int b = blockIdx.z, h = blockIdx.y, q0 = blockIdx.x << 6;

  const size_t qrow = ((size_t)(b * S_ + q0 + w * 16 + lr)) * D_ + h * 64;
  const s16x8 qf0 = *(const s16x8*)(Q + qrow + lg * 8);
  const s16x8 qf1 = *(const s16x8*)(Q + qrow + 32 + lg * 8);

  f32x4 accO[4];
  float m[4], ls[4];
#pragma unroll
  for (int i = 0; i < 4; ++i) { accO[i] = (f32x4)0.f; m[i] = -1e30f; ls[i] = 0.f; }

  for (int kt = 0; kt < S_; kt += 32) {
    f32x4 sc[2] = {(f32x4)0.f, (f32x4)0.f};
#pragma unroll
    for (int blk = 0; blk < 2; ++blk) {
      const size_t krow = ((size_t)(b * S_ + kt + blk * 16 + lr)) * D_ + h * 64;
      const s16x8 kf0 = *(const s16x8*)(K + krow + lg * 8);
      const s16x8 kf1 = *(const s16x8*)(K + krow + 32 + lg * 8);
      sc[blk] = mm(qf0, kf0, sc[blk]);
      sc[blk] = mm(qf1, kf1, sc[blk]);
    }
#pragma unroll
    for (int r = 0; r < 4; ++r) {
      const float s0 = sc[0][r] * SCALE_, s1 = sc[1][r] * SCALE_;
      float mx = fmaxf(s0, s1);
#pragma unroll
      for (int o = 8; o > 0; o >>= 1) mx = fmaxf(mx, __shfl_xor(mx, o));
      const float mn = fmaxf(m[r], mx);
      const float al = __expf(m[r] - mn);
      const float p0 = __expf(s0 - mn), p1 = __expf(s1 - mn);
      float ps = p0 + p1;
#pragma unroll
      for (int o = 8; o > 0; o >>= 1) ps += __shfl_xor(ps, o);
      ls[r] = ls[r] * al + ps;
      m[r] = mn;
#pragma unroll
      for (int dc = 0; dc < 4; ++dc) accO[dc][r] *= al;
      P_lds[w][lg * 4 + r][lr] = f2bf(p0);
      P_lds[w][lg * 4 + r][16 + lr] = f2bf(p1);
    }
    const s16x8 pa = *(const s16x8*)(&P_lds[w][lr][lg * 8]);
#pragma unroll
    for (int dc = 0; dc < 4; ++dc) {
      const size_t vrow = ((size_t)((b * H_ + h) * 64 + dc * 16 + lr)) * S_ + kt + lg * 8;
      const s16x8 vf = *(const s16x8*)(Vt + vrow);
      accO[dc] = mm(pa, vf, accO[dc]);
    }
  }
#pragma unroll
  for (int dc = 0; dc < 4; ++dc)
#pragma unroll
    for (int r = 0; r < 4; ++r) {
      const size_t orow = ((size_t)(b * S_ + q0 + w * 16 + lg * 4 + r)) * D_ + h * 64;
      O[orow + dc * 16 + lr] = f2bf(accO[dc][r] / ls[r]);
    }
}

// ---------- cross-attn scores: attn = SCALE * Qc.Kc^T (fp32 out) ------------
__global__ __launch_bounds__(256) void qk_cross(const u16* __restrict__ Q,
                                                const u16* __restrict__ K,
                                                float* __restrict__ attn) {
  const int t = threadIdx.x, l = t & 63, w = t >> 6;
  const int lr = l & 15, lg = l >> 4;
  const int bh = blockIdx.y, b = bh >> 3, h = bh & 7, q0 = blockIdx.x << 6;
  const size_t qrow = ((size_t)(b * S_ + q0 + w * 16 + lr)) * D_ + h * 64;
  const s16x8 qf0 = *(const s16x8*)(Q + qrow + lg * 8);
  const s16x8 qf1 = *(const s16x8*)(Q + qrow + 32 + lg * 8);
  for (int kt = 0; kt < S_; kt += 32) {
    f32x4 sc[2] = {(f32x4)0.f, (f32x4)0.f};
#pragma unroll
    for (int blk = 0; blk < 2; ++blk) {
      const size_t krow = ((size_t)(b * S_ + kt + blk * 16 + lr)) * D_ + h * 64;
      const s16x8 kf0 = *(const s16x8*)(K + krow + lg * 8);
      const s16x8 kf1 = *(const s16x8*)(K + krow + 32 + lg * 8);
      sc[blk] = mm(qf0, kf0, sc[blk]);
      sc[blk] = mm(qf1, kf1, sc[blk]);
    }
#pragma unroll
    for (int blk = 0; blk < 2; ++blk)
#pragma unroll
      for (int r = 0; r < 4; ++r)
        attn[((size_t)bh * S_ + q0 + w * 16 + lg * 4 + r) * S_ + kt + blk * 16 + lr] =
            sc[blk][r] * SCALE_;
  }
}

// ---------- row softmax in place (fp32 rows of 1024) ------------------------
__global__ __launch_bounds__(256) void softmax_rows(float* __restrict__ p) {
  __shared__ float sm[4];
  const int tid = threadIdx.x;
  float* row = p + (size_t)blockIdx.x * S_;
  float4 v = *(float4*)(row + (tid << 2));
  float mx = fmaxf(fmaxf(v.x, v.y), fmaxf(v.z, v.w));
#pragma unroll
  for (int off = 32; off > 0; off >>= 1) mx = fmaxf(mx, __shfl_xor(mx, off));
  if ((tid & 63) == 0) sm[tid >> 6] = mx;
  __syncthreads();
  mx = fmaxf(fmaxf(sm[0], sm[1]), fmaxf(sm[2], sm[3]));
  __syncthreads();
  float4 e = {__expf(v.x - mx), __expf(v.y - mx), __expf(v.z - mx), __expf(v.w - mx)};
  float s = e.x + e.y + e.z + e.w;
#pragma unroll
  for (int off = 32; off > 0; off >>= 1) s += __shfl_xor(s, off);
  if ((tid & 63) == 0) sm[tid >> 6] = s;
  __syncthreads();
  s = sm[0] + sm[1] + sm[2] + sm[3];
  const float inv = 1.0f / s;
  e.x *= inv; e.y *= inv; e.z *= inv; e.w *= inv;
  *(float4*)(row + (tid << 2)) = e;
}

// ---------- dual PV: ctx_{a,b} = attn @ V_{a,b} (Vt layouts) ----------------
__global__ __launch_bounds__(256) void pv_dual(const float* __restrict__ attn,
                                               const u16* __restrict__ VAt,
                                               const u16* __restrict__ VBt,
                                               u16* __restrict__ CA,
                                               u16* __restrict__ CB) {
  const int t = threadIdx.x, l = t & 63, w = t >> 6;
  const int lr = l & 15, lg = l >> 4;
  const int bh = blockIdx.y, b = bh >> 3, h = bh & 7, q0 = blockIdx.x << 6;
  f32x4 accA[4], accB[4];
#pragma unroll
  for (int i = 0; i < 4; ++i) { accA[i] = (f32x4)0.f; accB[i] = (f32x4)0.f; }
  const float* ap0 = attn + ((size_t)bh * S_ + q0 + w * 16 + lr) * S_ + lg * 8;
  for (int kt = 0; kt < S_; kt += 32) {
    const float4 a0 = *(const float4*)(ap0 + kt);
    const float4 a1 = *(const float4*)(ap0 + kt + 4);
    s16x8 pa;
    pa[0] = (short)f2bf(a0.x); pa[1] = (short)f2bf(a0.y);
    pa[2] = (short)f2bf(a0.z); pa[3] = (short)f2bf(a0.w);
    pa[4] = (short)f2bf(a1.x); pa[5] = (short)f2bf(a1.y);
    pa[6] = (short)f2bf(a1.z); pa[7] = (short)f2bf(a1.w);
#pragma unroll
    for (int dc = 0; dc < 4; ++dc) {
      const size_t vrow = ((size_t)((b * H_ + h) * 64 + dc * 16 + lr)) * S_ + kt + lg * 8;
      const s16x8 va = *(const s16x8*)(VAt + vrow);
      const s16x8 vb = *(const s16x8*)(VBt + vrow);
      accA[dc] = mm(pa, va, accA[dc]);
      accB[dc] = mm(pa, vb, accB[dc]);
    }
  }
#pragma unroll
  for (int dc = 0; dc < 4; ++dc)
#pragma unroll
    for (int r = 0; r < 4; ++r) {
      const size_t orow = ((size_t)(b * S_ + q0 + w * 16 + lg * 4 + r)) * D_ + h * 64;
      CA[orow + dc * 16 + lr] = f2bf(accA[dc][r]);
      CB[orow + dc * 16 + lr] = f2bf(accB[dc][r]);
    }
}

// ---------- y = LayerNorm(c + r); bf16 in; bf16 or fp32 out -----------------
template <int OUT32>
__global__ __launch_bounds__(128) void ln_res(const u16* __restrict__ c,
                                              const u16* __restrict__ r,
                                              void* __restrict__ y) {
  __shared__ float sm[2];
  const int tid = threadIdx.x;
  const size_t base = (size_t)blockIdx.x * D_ + (tid << 2);
  const u16x4 cv = *(const u16x4*)(c + base);
  const u16x4 rv = *(const u16x4*)(r + base);
  float v[4]; float s = 0.f;
#pragma unroll
  for (int i = 0; i < 4; ++i) { v[i] = bf2f(cv[i]) + bf2f(rv[i]); s += v[i]; }
#pragma unroll
  for (int off = 32; off > 0; off >>= 1) s += __shfl_xor(s, off);
  if ((tid & 63) == 0) sm[tid >> 6] = s;
  __syncthreads();
  const float mean = (sm[0] + sm[1]) * (1.0f / D_);
  __syncthreads();
  float sq = 0.f;
#pragma unroll
  for (int i = 0; i < 4; ++i) { v[i] -= mean; sq += v[i] * v[i]; }
#pragma unroll
  for (int off = 32; off > 0; off >>= 1) sq += __shfl_xor(sq, off);
  if ((tid & 63) == 0) sm[tid >> 6] = sq;
  __syncthreads();
  const float inv = rsqrtf((sm[0] + sm[1]) * (1.0f / D_) + EPS_);
  if (OUT32) {
    float4 o = {v[0] * inv, v[1] * inv, v[2] * inv, v[3] * inv};
    *(float4*)((float*)y + base) = o;
  } else {
    u16x4 o = {f2bf(v[0] * inv), f2bf(v[1] * inv), f2bf(v[2] * inv), f2bf(v[3] * inv)};
    *(u16x4*)((u16*)y + base) = o;
  }
}

extern "C" void kernel_launch(void* const* d_in, const int* in_sizes, int n_in,
                              void* d_out, int out_size, void* d_ws, size_t ws_size,
                              hipStream_t stream) {
  (void)in_sizes; (void)n_in; (void)out_size; (void)ws_size;
  const float* act = (const float*)d_in[0];
  const float* bg  = (const float*)d_in[1];
  const float* Wf[18] = {
      (const float*)d_in[2],  (const float*)d_in[3],  (const float*)d_in[4],
      (const float*)d_in[5],  (const float*)d_in[6],  (const float*)d_in[7],
      (const float*)d_in[8],  (const float*)d_in[9],  (const float*)d_in[10],
      (const float*)d_in[11], (const float*)d_in[12], (const float*)d_in[13],
      (const float*)d_in[14], (const float*)d_in[15], (const float*)d_in[16],
      (const float*)d_in[17], (const float*)d_in[18], (const float*)d_in[19]};
  // dims (K,N) per weight, in d_in order Wq..Fbb2
  const int wk[18] = {512, 512, 512, 512, 512, 512, 512, 512, 512, 512,
                      512, 2048, 512, 2048, 512, 2048, 512, 2048};
  const int wn[18] = {512, 512, 512, 512, 512, 512, 512, 512, 512, 512,
                      2048, 512, 2048, 512, 2048, 512, 2048, 512};

  float* outA = (float*)d_out;
  float* outB = outA + SLOT_;
  float* attn = outB + SLOT_;

  u16* wsp = (u16*)d_ws;
  u16* ss[11];
  for (int i = 0; i < 11; ++i) ss[i] = wsp + (size_t)i * SLOT_;
  u16* hid = wsp + (size_t)11 * SLOT_;             // 8192 x 2048
  u16* wt[18];
  u16* wcur = wsp + (size_t)15 * SLOT_;
  for (int i = 0; i < 18; ++i) { wt[i] = wcur; wcur += (size_t)wk[i] * wn[i]; }
  u16 *WqT = wt[0], *WkT = wt[1], *WvT = wt[2], *WoT = wt[3];
  u16 *AqT = wt[4], *AkT = wt[5], *AvaT = wt[6], *AvbT = wt[7];
  u16 *AfaT = wt[8], *AfbT = wt[9];
  u16 *Fa1T = wt[10], *Fa2T = wt[11], *Fb1T = wt[12], *Fb2T = wt[13];
  u16 *Faa1T = wt[14], *Faa2T = wt[15], *Fbb1T = wt[16], *Fbb2T = wt[17];

  // casts + weight transposes
  cast_bf<<<4096, 256, 0, stream>>>(act, ss[0]);
  cast_bf<<<4096, 256, 0, stream>>>(bg, ss[1]);
  for (int i = 0; i < 18; ++i)
    wtrans<<<dim3(wn[i] >> 6, wk[i] >> 6), 256, 0, stream>>>(Wf[i], wt[i], wk[i], wn[i]);

  auto G = [&](const u16* A, const u16* Bt, u16* C, int N, int K, int relu, int vout) {
    dim3 g(N >> 7, NROW_ >> 7);
    if (relu)
      hipLaunchKernelGGL((gemm_nt<1, 0>), g, dim3(256), 0, stream, A, Bt, C, N, K);
    else if (vout)
      hipLaunchKernelGGL((gemm_nt<0, 1>), g, dim3(256), 0, stream, A, Bt, C, N, K);
    else
      hipLaunchKernelGGL((gemm_nt<0, 0>), g, dim3(256), 0, stream, A, Bt, C, N, K);
  };
  const dim3 ag(S_ / 64, H_, 8);
  const dim3 cg(S_ / 64, 64);

  // ---- action self-attention + FFN ----
  G(ss[0], WqT, ss[2], 512, 512, 0, 0);
  G(ss[0], WkT, ss[3], 512, 512, 0, 0);
  G(ss[0], WvT, ss[4], 512, 512, 0, 1);            // Vt
  attn_flash<<<ag, 256, 0, stream>>>(ss[2], ss[3], ss[4], ss[5]);
  G(ss[5], WoT, ss[6], 512, 512, 0, 0);
  ln_res<0><<<NROW_, 128, 0, stream>>>(ss[6], ss[0], ss[7]);       // xa
  G(ss[7], Fa1T, hid, 2048, 512, 1, 0);
  G(hid, Fa2T, ss[6], 512, 2048, 0, 0);
  ln_res<0><<<NROW_, 128, 0, stream>>>(ss[6], ss[7], ss[8]);       // xa2

  // ---- background self-attention + FFN ----
  G(ss[1], WqT, ss[2], 512, 512, 0, 0);
  G(ss[1], WkT, ss[3], 512, 512, 0, 0);
  G(ss[1], WvT, ss[4], 512, 512, 0, 1);
  attn_flash<<<ag, 256, 0, stream>>>(ss[2], ss[3], ss[4], ss[5]);
  G(ss[5], WoT, ss[6], 512, 512, 0, 0);
  ln_res<0><<<NROW_, 128, 0, stream>>>(ss[6], ss[1], ss[9]);       // xb
  G(ss[9], Fb1T, hid, 2048, 512, 1, 0);
  G(hid, Fb2T, ss[6], 512, 2048, 0, 0);
  ln_res<0><<<NROW_, 128, 0, stream>>>(ss[6], ss[9], ss[10]);      // xb2

  // ---- ABI cross-attention ----
  G(ss[8], AqT, ss[2], 512, 512, 0, 0);            // Qc
  G(ss[10], AkT, ss[3], 512, 512, 0, 0);           // Kc
  G(ss[8], AvaT, ss[4], 512, 512, 0, 1);           // VAt
  G(ss[10], AvbT, ss[5], 512, 512, 0, 1);          // VBt
  qk_cross<<<cg, 256, 0, stream>>>(ss[2], ss[3], attn);
  softmax_rows<<<64 * S_, 256, 0, stream>>>(attn);
  pv_dual<<<cg, 256, 0, stream>>>(attn, ss[4], ss[5], ss[2], ss[3]);  // ctx_a, ctx_b
  G(ss[2], AfaT, ss[6], 512, 512, 0, 0);
  ln_res<0><<<NROW_, 128, 0, stream>>>(ss[6], ss[8], ss[7]);       // oa_mid
  G(ss[3], AfbT, ss[4], 512, 512, 0, 0);
  ln_res<0><<<NROW_, 128, 0, stream>>>(ss[4], ss[10], ss[9]);      // ob_mid

  // ---- final FFNs ----
  G(ss[7], Faa1T, hid, 2048, 512, 1, 0);
  G(hid, Faa2T, ss[6], 512, 2048, 0, 0);
  ln_res<1><<<NROW_, 128, 0, stream>>>(ss[6], ss[7], outA);
  G(ss[9], Fbb1T, hid, 2048, 512, 1, 0);
  G(hid, Fbb2T, ss[6], 512, 2048, 0, 0);
  ln_res<1><<<NROW_, 128, 0, stream>>>(ss[6], ss[9], outB);
}